// Round 6
// baseline (180.041 us; speedup 1.0000x reference)
//
#include <hip/hip_runtime.h>
#include <math.h>

#define VOCAB 100000
#define DIM 128
#define BATCH 4096
#define CTX 20
#define NEGS 10
#define NTARG (CTX + CTX * NEGS)           // 220
#define NPAIR_POS (CTX * BATCH)            // 81920
#define NPAIR (NPAIR_POS + BATCH * CTX * NEGS)  // 901120
#define CAP 48
#define SPILL_MAX 2048
#define SPILL_BLOCKS 8

// d_ws layout (bytes)
#define OFF_COUNTS   0u                    // u32[VOCAB]      400000
#define OFF_SPILLCNT 400000u               // u32             4
#define OFF_SPILL    400128u               // u32[SPILL_MAX]  8192
#define OFF_BUCKETS  408320u               // u16[VOCAB*CAP]  9600000
#define OFF_IVEC     10008320u             // f32[BATCH*DIM]  2097152 (16-aligned)
#define WS_NEEDED    12105472u

__device__ __forceinline__ float log_sigmoid_fast(float x) {
    float a = fabsf(x);
    return fminf(x, 0.0f) - __logf(1.0f + __expf(-a));
}

// ---- Kernel A: ivec[b] = W_i[i_words[b]]  (dense 2 MB stage) ----
__global__ __launch_bounds__(256) void gather_ivec_kernel(
    const int* __restrict__ i_words, const float4* __restrict__ W_i4,
    float4* __restrict__ ivec4)
{
    int tid = blockIdx.x * 256 + threadIdx.x;   // 131072 = BATCH*32
    int b = tid >> 5, q = tid & 31;
    int ic = i_words[b];
    ivec4[tid] = W_i4[ic * 32 + q];
    (void)b;
}

// ---- Kernel B: scatter pairs into per-row buckets ----
__global__ __launch_bounds__(256) void scatter_kernel(
    const int* __restrict__ o_words, const int* __restrict__ n_words,
    unsigned* __restrict__ counts, unsigned* __restrict__ spillcnt,
    unsigned* __restrict__ spill, unsigned short* __restrict__ buckets)
{
    int j = blockIdx.x * 256 + threadIdx.x;     // NPAIR = 3520*256 exactly
    int r; unsigned rec;
    if (j < NPAIR_POS) {
        r = o_words[j];                          // [C,B] flat; b = j & 4095
        rec = (unsigned)(j & (BATCH - 1));
    } else {
        int jn = j - NPAIR_POS;                  // [B, C*NEG] flat
        r = n_words[jn];
        rec = (unsigned)(jn / (CTX * NEGS)) | 4096u;   // b | neg-bit
    }
    unsigned pos = atomicAdd(&counts[r], 1u);
    if (pos < CAP) {
        buckets[(unsigned)r * CAP + pos] = (unsigned short)rec;
    } else {
        unsigned s = atomicAdd(spillcnt, 1u);
        if (s < SPILL_MAX) spill[s] = ((unsigned)r << 13) | rec;
    }
}

// ---- Kernel C: per-row streaming dot products + loss ----
__global__ __launch_bounds__(256) void row_loss_kernel(
    const float* __restrict__ W_os, const float* __restrict__ ivec,
    const unsigned* __restrict__ counts, const unsigned short* __restrict__ buckets,
    const unsigned* __restrict__ spillcnt, const unsigned* __restrict__ spill,
    float* __restrict__ out)
{
    const int t    = threadIdx.x & 15;
    const int lane = threadIdx.x & 63;
    const int wave = threadIdx.x >> 6;
    const int gid  = blockIdx.x * 16 + (threadIdx.x >> 4);

    float acc = 0.0f;

    if (gid < VOCAB) {
        unsigned cnt = counts[gid]; if (cnt > CAP) cnt = CAP;
        if (cnt) {
            const float4* row = (const float4*)(W_os + (size_t)gid * DIM);
            float4 r0 = row[t], r1 = row[t + 16];    // contiguous 256B per instr
            for (unsigned k = 0; k < cnt; ++k) {
                unsigned rec = buckets[(unsigned)gid * CAP + k];
                const float4* ivp = (const float4*)(ivec + ((rec & 4095u) << 7));
                float4 v0 = ivp[t], v1 = ivp[t + 16];
                float p = r0.x*v0.x + r0.y*v0.y + r0.z*v0.z + r0.w*v0.w
                        + r1.x*v1.x + r1.y*v1.y + r1.z*v1.z + r1.w*v1.w;
                p += __shfl_xor(p, 1);
                p += __shfl_xor(p, 2);
                p += __shfl_xor(p, 4);
                p += __shfl_xor(p, 8);
                float term = (rec & 4096u)
                           ? (1.0f / NEGS) * log_sigmoid_fast(-p)
                           : (1.0f / CTX)  * log_sigmoid_fast(p);
                acc += (t == 0) ? term : 0.0f;
            }
        }
    } else {
        // spill groups: exact handling of bucket-overflow pairs
        int sg = gid - VOCAB;                       // 0 .. 16*SPILL_BLOCKS-1
        unsigned ns = *spillcnt; if (ns > SPILL_MAX) ns = SPILL_MAX;
        for (unsigned s = sg; s < ns; s += 16 * SPILL_BLOCKS) {
            unsigned e = spill[s];
            unsigned r = e >> 13, rec = e & 8191u;
            const float4* row = (const float4*)(W_os + (size_t)r * DIM);
            float4 r0 = row[t], r1 = row[t + 16];
            const float4* ivp = (const float4*)(ivec + ((rec & 4095u) << 7));
            float4 v0 = ivp[t], v1 = ivp[t + 16];
            float p = r0.x*v0.x + r0.y*v0.y + r0.z*v0.z + r0.w*v0.w
                    + r1.x*v1.x + r1.y*v1.y + r1.z*v1.z + r1.w*v1.w;
            p += __shfl_xor(p, 1);
            p += __shfl_xor(p, 2);
            p += __shfl_xor(p, 4);
            p += __shfl_xor(p, 8);
            float term = (rec & 4096u)
                       ? (1.0f / NEGS) * log_sigmoid_fast(-p)
                       : (1.0f / CTX)  * log_sigmoid_fast(p);
            acc += (t == 0) ? term : 0.0f;
        }
    }

    // acc nonzero on lanes 0,16,32,48 -> wave reduce
    acc += __shfl_xor(acc, 16);
    acc += __shfl_xor(acc, 32);

    __shared__ float ws[4];
    if (lane == 0) ws[wave] = acc;
    __syncthreads();
    if (threadIdx.x == 0) {
        float s = ws[0] + ws[1] + ws[2] + ws[3];
        if (s != 0.0f) atomicAdd(out, -s);
    }
}

// ---- Fallback (round-5 direct kernel) if ws too small ----
__global__ __launch_bounds__(256) void sgns_loss_direct(
    const int* __restrict__ i_words, const int* __restrict__ o_words,
    const int* __restrict__ n_words, const float* __restrict__ W_i,
    const float* __restrict__ W_os, float* __restrict__ out)
{
    const int lane = threadIdx.x & 63;
    const int wave = threadIdx.x >> 6;
    const int w    = blockIdx.x * 4 + wave;
    const int b    = w >> 1;
    const int h    = w & 1;
    const int sub = lane >> 4;
    const int t   = lane & 15;
    const int j_begin = h ? 112 : 0;
    const int j_end   = h ? NTARG : 112;
    float acc = 0.0f;
    const int ic = i_words[b];
    const char* ibase = (const char*)W_i + (((unsigned)ic << 9) + ((unsigned)t << 5));
    float4 i0 = *(const float4*)(ibase);
    float4 i1 = *(const float4*)(ibase + 16);
    #pragma unroll 4
    for (int j0 = j_begin; j0 < j_end; j0 += 4) {
        int jj = j0 + sub;
        int idx; float sgn, wgt;
        if (jj < CTX) { idx = o_words[jj * BATCH + b]; sgn = 1.0f; wgt = 1.0f / CTX; }
        else { idx = n_words[b * (CTX * NEGS) + (jj - CTX)]; sgn = -1.0f; wgt = 1.0f / NEGS; }
        const char* obase = (const char*)W_os + (((unsigned)idx << 9) + ((unsigned)t << 5));
        float4 o0 = *(const float4*)(obase);
        float4 o1 = *(const float4*)(obase + 16);
        float p = i0.x*o0.x + i0.y*o0.y + i0.z*o0.z + i0.w*o0.w
                + i1.x*o1.x + i1.y*o1.y + i1.z*o1.z + i1.w*o1.w;
        p += __shfl_xor(p, 1); p += __shfl_xor(p, 2);
        p += __shfl_xor(p, 4); p += __shfl_xor(p, 8);
        acc += (t == 0) ? wgt * log_sigmoid_fast(sgn * p) : 0.0f;
    }
    acc += __shfl_xor(acc, 16);
    acc += __shfl_xor(acc, 32);
    __shared__ float ws[4];
    if (lane == 0) ws[wave] = acc;
    __syncthreads();
    if (threadIdx.x == 0) atomicAdd(out, -(ws[0] + ws[1] + ws[2] + ws[3]));
}

extern "C" void kernel_launch(void* const* d_in, const int* in_sizes, int n_in,
                              void* d_out, int out_size, void* d_ws, size_t ws_size,
                              hipStream_t stream) {
    const int*   i_words = (const int*)d_in[0];
    const int*   o_words = (const int*)d_in[1];
    const int*   n_words = (const int*)d_in[2];
    const float* W_i     = (const float*)d_in[3];
    const float* W_os    = (const float*)d_in[4];
    float* out = (float*)d_out;

    hipMemsetAsync(out, 0, sizeof(float), stream);

    if (ws_size < (size_t)WS_NEEDED) {
        sgns_loss_direct<<<2048, 256, 0, stream>>>(i_words, o_words, n_words, W_i, W_os, out);
        return;
    }

    char* ws = (char*)d_ws;
    unsigned*       counts   = (unsigned*)(ws + OFF_COUNTS);
    unsigned*       spillcnt = (unsigned*)(ws + OFF_SPILLCNT);
    unsigned*       spill    = (unsigned*)(ws + OFF_SPILL);
    unsigned short* buckets  = (unsigned short*)(ws + OFF_BUCKETS);
    float*          ivec     = (float*)(ws + OFF_IVEC);

    // zero counts + spillcnt every call (harness does not re-poison/zero ws)
    hipMemsetAsync(ws, 0, OFF_SPILLCNT + 4, stream);

    gather_ivec_kernel<<<512, 256, 0, stream>>>(i_words, (const float4*)W_i, (float4*)ivec);
    scatter_kernel<<<NPAIR / 256, 256, 0, stream>>>(o_words, n_words, counts, spillcnt, spill, buckets);
    row_loss_kernel<<<VOCAB / 16 + SPILL_BLOCKS, 256, 0, stream>>>(
        W_os, ivec, counts, buckets, spillcnt, spill, out);
}

// Round 7
// 94.972 us; speedup vs baseline: 1.8957x; 1.8957x over previous
//
#include <hip/hip_runtime.h>
#include <math.h>

#define VOCAB 100000
#define DIM 128
#define BATCH 4096
#define CTX 20
#define NEGS 10
#define NTARG (CTX + CTX * NEGS)                 // 220
#define NPAIR_POS (CTX * BATCH)                  // 81920
#define NPAIR (NPAIR_POS + BATCH * CTX * NEGS)   // 901120
#define NB 64            // buckets (1563 rows each)
#define ROWS_PER_B 1563
#define P1B 128          // pass-1 blocks
#define PAIRS_PER_P1B (NPAIR / P1B)              // 7040
#define CAPB 256         // slots per (bucket, pass1-block); lambda=110, >13 sigma
#define SPILL_MAX 2048

// d_ws layout (bytes)
#define OFF_RECORDS  0u                          // u32[NB*P1B*CAPB] = 8388608
#define OFF_COUNTS   8388608u                    // u32[NB*P1B]      = 32768
#define OFF_SPILLCNT 8421376u                    // u32
#define OFF_SPILL    8421632u                    // u32[SPILL_MAX]   = 8192
#define OFF_IVEC     8429824u                    // f32[BATCH*DIM]   = 2097152
#define WS_NEEDED    10526976u

__device__ __forceinline__ float log_sigmoid_fast(float x) {
    float a = fabsf(x);
    return fminf(x, 0.0f) - __logf(1.0f + __expf(-a));
}

// ---- Kernel A: ivec[b] = W_i[i_words[b]] (dense 2 MB stage) ----
__global__ __launch_bounds__(256) void gather_ivec_kernel(
    const int* __restrict__ i_words, const float4* __restrict__ W_i4,
    float4* __restrict__ ivec4)
{
    int tid = blockIdx.x * 256 + threadIdx.x;   // 131072 = BATCH*32
    int b = tid >> 5, q = tid & 31;
    int ic = i_words[b];
    ivec4[tid] = W_i4[ic * 32 + q];
}

// ---- Kernel B: bucketize pairs; LDS atomics only, static per-block regions ----
__global__ __launch_bounds__(256) void bucketize_kernel(
    const int* __restrict__ o_words, const int* __restrict__ n_words,
    unsigned* __restrict__ records, unsigned* __restrict__ counts,
    unsigned* __restrict__ spillcnt, unsigned* __restrict__ spill)
{
    __shared__ unsigned lcnt[NB];
    if (threadIdx.x < NB) lcnt[threadIdx.x] = 0;
    __syncthreads();

    const int base = blockIdx.x * PAIRS_PER_P1B;
    const int end  = base + PAIRS_PER_P1B;
    for (int j = base + threadIdx.x; j < end; j += 256) {
        int row; unsigned rec;
        if (j < NPAIR_POS) {                        // o_words flat [C,B]: b = j & 4095
            row = o_words[j];
            rec = ((unsigned)row << 13) | ((unsigned)(j & (BATCH - 1)) << 1);
        } else {                                    // n_words flat [B, C*NEG]
            int jn = j - NPAIR_POS;
            row = n_words[jn];
            rec = ((unsigned)row << 13) | ((unsigned)(jn / (CTX * NEGS)) << 1) | 1u;
        }
        int bin = row / ROWS_PER_B;                 // 0..63
        unsigned slot = atomicAdd(&lcnt[bin], 1u);  // LDS atomic
        if (slot < CAPB) {
            records[((unsigned)bin << 15) | ((unsigned)blockIdx.x << 8) | slot] = rec;
        } else {
            unsigned s = atomicAdd(spillcnt, 1u);   // ~never taken
            if (s < SPILL_MAX) spill[s] = rec;
        }
    }
    __syncthreads();
    if (threadIdx.x < NB) {
        unsigned c = lcnt[threadIdx.x];
        counts[((unsigned)threadIdx.x << 7) | blockIdx.x] = (c > CAPB) ? CAPB : c;
    }
}

// ---- Kernel C: per-bucket pair processing, XCD-affine ----
__global__ __launch_bounds__(256) void bucket_loss_kernel(
    const float* __restrict__ W_os, const float* __restrict__ ivec,
    const unsigned* __restrict__ records, const unsigned* __restrict__ counts,
    const unsigned* __restrict__ spillcnt, const unsigned* __restrict__ spill,
    float* __restrict__ out)
{
    const int t    = threadIdx.x & 15;
    const int grp  = threadIdx.x >> 4;
    const int lane = threadIdx.x & 63;
    const int wave = threadIdx.x >> 6;

    float acc = 0.0f;
    const int lid = blockIdx.x;

    if (lid < 1024) {
        const int xcd = lid & 7;
        const int seq = lid >> 3;                   // 0..127 per XCD
        const int bucket = xcd + ((seq >> 4) << 3); // 8 sequential buckets per XCD
        const int sub = seq & 15;                   // 16 blocks per bucket
        for (int pc = 0; pc < 8; ++pc) {            // 8 chunks per block
            const int p = (sub << 3) + pc;
            unsigned cnt = counts[((unsigned)bucket << 7) + p];
            const unsigned* rbase = records + (((unsigned)bucket << 15) | ((unsigned)p << 8));
            for (unsigned i = grp; i < cnt; i += 16) {
                unsigned rec = rbase[i];
                unsigned row = rec >> 13, bb = (rec >> 1) & 4095u;
                const float4* rp = (const float4*)(W_os + row * DIM);
                float4 r0 = rp[t], r1 = rp[t + 16];
                const float4* vp = (const float4*)(ivec + (bb << 7));
                float4 v0 = vp[t], v1 = vp[t + 16];
                float pd = r0.x*v0.x + r0.y*v0.y + r0.z*v0.z + r0.w*v0.w
                         + r1.x*v1.x + r1.y*v1.y + r1.z*v1.z + r1.w*v1.w;
                pd += __shfl_xor(pd, 1);
                pd += __shfl_xor(pd, 2);
                pd += __shfl_xor(pd, 4);
                pd += __shfl_xor(pd, 8);
                float term = (rec & 1u) ? (1.0f / NEGS) * log_sigmoid_fast(-pd)
                                        : (1.0f / CTX)  * log_sigmoid_fast(pd);
                if (t == 0) acc += term;
            }
        }
    } else {
        // spill blocks (exactness guarantee; expected empty)
        int sg = (lid - 1024) * 16 + grp;           // 0..127
        unsigned ns = *spillcnt; if (ns > SPILL_MAX) ns = SPILL_MAX;
        for (unsigned s = sg; s < ns; s += 128) {
            unsigned rec = spill[s];
            unsigned row = rec >> 13, bb = (rec >> 1) & 4095u;
            const float4* rp = (const float4*)(W_os + row * DIM);
            float4 r0 = rp[t], r1 = rp[t + 16];
            const float4* vp = (const float4*)(ivec + (bb << 7));
            float4 v0 = vp[t], v1 = vp[t + 16];
            float pd = r0.x*v0.x + r0.y*v0.y + r0.z*v0.z + r0.w*v0.w
                     + r1.x*v1.x + r1.y*v1.y + r1.z*v1.z + r1.w*v1.w;
            pd += __shfl_xor(pd, 1);
            pd += __shfl_xor(pd, 2);
            pd += __shfl_xor(pd, 4);
            pd += __shfl_xor(pd, 8);
            float term = (rec & 1u) ? (1.0f / NEGS) * log_sigmoid_fast(-pd)
                                    : (1.0f / CTX)  * log_sigmoid_fast(pd);
            if (t == 0) acc += term;
        }
    }

    acc += __shfl_xor(acc, 16);
    acc += __shfl_xor(acc, 32);
    __shared__ float wsum[4];
    if (lane == 0) wsum[wave] = acc;
    __syncthreads();
    if (threadIdx.x == 0) {
        float s = wsum[0] + wsum[1] + wsum[2] + wsum[3];
        if (s != 0.0f) atomicAdd(out, -s);
    }
}

// ---- Fallback (round-5 direct kernel) if ws too small ----
__global__ __launch_bounds__(256) void sgns_loss_direct(
    const int* __restrict__ i_words, const int* __restrict__ o_words,
    const int* __restrict__ n_words, const float* __restrict__ W_i,
    const float* __restrict__ W_os, float* __restrict__ out)
{
    const int lane = threadIdx.x & 63;
    const int wave = threadIdx.x >> 6;
    const int w    = blockIdx.x * 4 + wave;
    const int b    = w >> 1;
    const int h    = w & 1;
    const int sub = lane >> 4;
    const int t   = lane & 15;
    const int j_begin = h ? 112 : 0;
    const int j_end   = h ? NTARG : 112;
    float acc = 0.0f;
    const int ic = i_words[b];
    const char* ibase = (const char*)W_i + (((unsigned)ic << 9) + ((unsigned)t << 5));
    float4 i0 = *(const float4*)(ibase);
    float4 i1 = *(const float4*)(ibase + 16);
    #pragma unroll 4
    for (int j0 = j_begin; j0 < j_end; j0 += 4) {
        int jj = j0 + sub;
        int idx; float sgn, wgt;
        if (jj < CTX) { idx = o_words[jj * BATCH + b]; sgn = 1.0f; wgt = 1.0f / CTX; }
        else { idx = n_words[b * (CTX * NEGS) + (jj - CTX)]; sgn = -1.0f; wgt = 1.0f / NEGS; }
        const char* obase = (const char*)W_os + (((unsigned)idx << 9) + ((unsigned)t << 5));
        float4 o0 = *(const float4*)(obase);
        float4 o1 = *(const float4*)(obase + 16);
        float p = i0.x*o0.x + i0.y*o0.y + i0.z*o0.z + i0.w*o0.w
                + i1.x*o1.x + i1.y*o1.y + i1.z*o1.z + i1.w*o1.w;
        p += __shfl_xor(p, 1); p += __shfl_xor(p, 2);
        p += __shfl_xor(p, 4); p += __shfl_xor(p, 8);
        acc += (t == 0) ? wgt * log_sigmoid_fast(sgn * p) : 0.0f;
    }
    acc += __shfl_xor(acc, 16);
    acc += __shfl_xor(acc, 32);
    __shared__ float ws[4];
    if (lane == 0) ws[wave] = acc;
    __syncthreads();
    if (threadIdx.x == 0) atomicAdd(out, -(ws[0] + ws[1] + ws[2] + ws[3]));
}

extern "C" void kernel_launch(void* const* d_in, const int* in_sizes, int n_in,
                              void* d_out, int out_size, void* d_ws, size_t ws_size,
                              hipStream_t stream) {
    const int*   i_words = (const int*)d_in[0];
    const int*   o_words = (const int*)d_in[1];
    const int*   n_words = (const int*)d_in[2];
    const float* W_i     = (const float*)d_in[3];
    const float* W_os    = (const float*)d_in[4];
    float* out = (float*)d_out;

    hipMemsetAsync(out, 0, sizeof(float), stream);

    if (ws_size < (size_t)WS_NEEDED) {
        sgns_loss_direct<<<2048, 256, 0, stream>>>(i_words, o_words, n_words, W_i, W_os, out);
        return;
    }

    char* ws = (char*)d_ws;
    unsigned* records  = (unsigned*)(ws + OFF_RECORDS);
    unsigned* counts   = (unsigned*)(ws + OFF_COUNTS);
    unsigned* spillcnt = (unsigned*)(ws + OFF_SPILLCNT);
    unsigned* spill    = (unsigned*)(ws + OFF_SPILL);
    float*    ivec     = (float*)(ws + OFF_IVEC);

    hipMemsetAsync(spillcnt, 0, sizeof(unsigned), stream);

    gather_ivec_kernel<<<512, 256, 0, stream>>>(i_words, (const float4*)W_i, (float4*)ivec);
    bucketize_kernel<<<P1B, 256, 0, stream>>>(o_words, n_words, records, counts, spillcnt, spill);
    bucket_loss_kernel<<<1024 + 8, 256, 0, stream>>>(W_os, ivec, records, counts, spillcnt, spill, out);
}

// Round 8
// 88.547 us; speedup vs baseline: 2.0333x; 1.0726x over previous
//
#include <hip/hip_runtime.h>
#include <math.h>

#define VOCAB 100000
#define DIM 128
#define BATCH 4096
#define CTX 20
#define NEGS 10
#define NTARG (CTX + CTX * NEGS)                 // 220
#define NPAIR_POS (CTX * BATCH)                  // 81920
#define NPAIR (NPAIR_POS + BATCH * CTX * NEGS)   // 901120
#define NB 32            // buckets: 3125 rows = 1.6 MB W_os slice each
#define ROWS_PER_B 3125
#define P1B 128          // pass-1 blocks (= cells per bucket)
#define PAIRS_PER_P1B (NPAIR / P1B)              // 7040
#define CAPB 384         // slots per cell; lambda=220, sigma~14.8 -> +11 sigma
#define SPILL_MAX 2048

// d_ws layout (bytes)
#define OFF_RECORDS  0u                          // u32[NB*P1B*CAPB] = 6291456
#define OFF_COUNTS   6291456u                    // u32[NB*P1B]      = 16384
#define OFF_SPILLCNT 6307840u                    // u32 (+pad)
#define OFF_SPILL    6308096u                    // u32[SPILL_MAX]   = 8192
#define OFF_IVEC     6316288u                    // f32[BATCH*DIM]   = 2097152
#define WS_NEEDED    8413440u

__device__ __forceinline__ float log_sigmoid_fast(float x) {
    float a = fabsf(x);
    return fminf(x, 0.0f) - __logf(1.0f + __expf(-a));
}

// ---- Kernel A: ivec[b] = W_i[i_words[b]] (dense 2 MB stage) ----
__global__ __launch_bounds__(256) void gather_ivec_kernel(
    const int* __restrict__ i_words, const float4* __restrict__ W_i4,
    float4* __restrict__ ivec4)
{
    int tid = blockIdx.x * 256 + threadIdx.x;   // 131072 = BATCH*32
    int b = tid >> 5, q = tid & 31;
    int ic = i_words[b];
    ivec4[tid] = W_i4[ic * 32 + q];
}

// ---- Kernel B: bucketize pairs; LDS atomics, static per-(bucket,block) cells ----
__global__ __launch_bounds__(256) void bucketize_kernel(
    const int* __restrict__ o_words, const int* __restrict__ n_words,
    unsigned* __restrict__ records, unsigned* __restrict__ counts,
    unsigned* __restrict__ spillcnt, unsigned* __restrict__ spill)
{
    __shared__ unsigned lcnt[NB];
    if (threadIdx.x < NB) lcnt[threadIdx.x] = 0;
    __syncthreads();

    const int base = blockIdx.x * PAIRS_PER_P1B;
    const int end  = base + PAIRS_PER_P1B;
    for (int j = base + threadIdx.x; j < end; j += 256) {
        int row; unsigned rec;
        if (j < NPAIR_POS) {                        // o_words flat [C,B]: b = j & 4095
            row = o_words[j];
            rec = ((unsigned)row << 13) | ((unsigned)(j & (BATCH - 1)) << 1);
        } else {                                    // n_words flat [B, C*NEG]
            int jn = j - NPAIR_POS;
            row = n_words[jn];
            rec = ((unsigned)row << 13) | ((unsigned)(jn / (CTX * NEGS)) << 1) | 1u;
        }
        int bin = (unsigned)row / ROWS_PER_B;       // 0..31 (magic-mul div)
        unsigned slot = atomicAdd(&lcnt[bin], 1u);  // LDS atomic
        if (slot < CAPB) {
            records[((unsigned)bin * P1B + (unsigned)blockIdx.x) * CAPB + slot] = rec;
        } else {
            unsigned s = atomicAdd(spillcnt, 1u);   // ~never taken
            if (s < SPILL_MAX) spill[s] = rec;
        }
    }
    __syncthreads();
    if (threadIdx.x < NB) {
        unsigned c = lcnt[threadIdx.x];
        counts[threadIdx.x * P1B + blockIdx.x] = (c > CAPB) ? CAPB : c;
    }
}

// ---- Kernel C: XCD-affine, in-phase bucket walk; one cell per block per bucket ----
__global__ __launch_bounds__(256) void bucket_loss_kernel(
    const float* __restrict__ W_os, const float* __restrict__ ivec,
    const unsigned* __restrict__ records, const unsigned* __restrict__ counts,
    const unsigned* __restrict__ spillcnt, const unsigned* __restrict__ spill,
    float* __restrict__ out)
{
    const int t    = threadIdx.x & 15;
    const int grp  = threadIdx.x >> 4;
    const int lane = threadIdx.x & 63;
    const int wave = threadIdx.x >> 6;

    float acc = 0.0f;
    const int lid = blockIdx.x;

    if (lid < 1024) {
        const int xcd = lid & 7;                    // blockIdx%8 -> XCD (heuristic)
        const int sub = lid >> 3;                   // 0..127: cell within bucket
        for (int bk = 0; bk < NB / 8; ++bk) {       // 4 buckets per XCD, in-phase walk
            const int bucket = xcd * (NB / 8) + bk;
            const unsigned cell = (unsigned)bucket * P1B + sub;
            unsigned cnt = counts[cell];
            const unsigned* rbase = records + cell * CAPB;
            #pragma unroll 4
            for (unsigned i = grp; i < cnt; i += 16) {
                unsigned rec = rbase[i];
                unsigned row = rec >> 13, bb = (rec >> 1) & 4095u;
                const char* rp = (const char*)W_os + ((row << 9) + ((unsigned)t << 5));
                float4 r0 = *(const float4*)rp;
                float4 r1 = *(const float4*)(rp + 16);
                const char* vp = (const char*)ivec + ((bb << 9) + ((unsigned)t << 5));
                float4 v0 = *(const float4*)vp;
                float4 v1 = *(const float4*)(vp + 16);
                float pd = r0.x*v0.x + r0.y*v0.y + r0.z*v0.z + r0.w*v0.w
                         + r1.x*v1.x + r1.y*v1.y + r1.z*v1.z + r1.w*v1.w;
                pd += __shfl_xor(pd, 1);
                pd += __shfl_xor(pd, 2);
                pd += __shfl_xor(pd, 4);
                pd += __shfl_xor(pd, 8);
                float term = (rec & 1u) ? (1.0f / NEGS) * log_sigmoid_fast(-pd)
                                        : (1.0f / CTX)  * log_sigmoid_fast(pd);
                if (t == 0) acc += term;
            }
        }
    } else {
        // spill blocks (exactness guarantee; expected empty)
        int sg = (lid - 1024) * 16 + grp;           // 0..127
        unsigned ns = *spillcnt; if (ns > SPILL_MAX) ns = SPILL_MAX;
        for (unsigned s = sg; s < ns; s += 128) {
            unsigned rec = spill[s];
            unsigned row = rec >> 13, bb = (rec >> 1) & 4095u;
            const char* rp = (const char*)W_os + ((row << 9) + ((unsigned)t << 5));
            float4 r0 = *(const float4*)rp;
            float4 r1 = *(const float4*)(rp + 16);
            const char* vp = (const char*)ivec + ((bb << 9) + ((unsigned)t << 5));
            float4 v0 = *(const float4*)vp;
            float4 v1 = *(const float4*)(vp + 16);
            float pd = r0.x*v0.x + r0.y*v0.y + r0.z*v0.z + r0.w*v0.w
                     + r1.x*v1.x + r1.y*v1.y + r1.z*v1.z + r1.w*v1.w;
            pd += __shfl_xor(pd, 1);
            pd += __shfl_xor(pd, 2);
            pd += __shfl_xor(pd, 4);
            pd += __shfl_xor(pd, 8);
            float term = (rec & 1u) ? (1.0f / NEGS) * log_sigmoid_fast(-pd)
                                    : (1.0f / CTX)  * log_sigmoid_fast(pd);
            if (t == 0) acc += term;
        }
    }

    acc += __shfl_xor(acc, 16);
    acc += __shfl_xor(acc, 32);
    __shared__ float wsum[4];
    if (lane == 0) wsum[wave] = acc;
    __syncthreads();
    if (threadIdx.x == 0) {
        float s = wsum[0] + wsum[1] + wsum[2] + wsum[3];
        if (s != 0.0f) atomicAdd(out, -s);
    }
}

// ---- Fallback (round-5 direct kernel) if ws too small ----
__global__ __launch_bounds__(256) void sgns_loss_direct(
    const int* __restrict__ i_words, const int* __restrict__ o_words,
    const int* __restrict__ n_words, const float* __restrict__ W_i,
    const float* __restrict__ W_os, float* __restrict__ out)
{
    const int lane = threadIdx.x & 63;
    const int wave = threadIdx.x >> 6;
    const int w    = blockIdx.x * 4 + wave;
    const int b    = w >> 1;
    const int h    = w & 1;
    const int sub = lane >> 4;
    const int t   = lane & 15;
    const int j_begin = h ? 112 : 0;
    const int j_end   = h ? NTARG : 112;
    float acc = 0.0f;
    const int ic = i_words[b];
    const char* ibase = (const char*)W_i + (((unsigned)ic << 9) + ((unsigned)t << 5));
    float4 i0 = *(const float4*)(ibase);
    float4 i1 = *(const float4*)(ibase + 16);
    #pragma unroll 4
    for (int j0 = j_begin; j0 < j_end; j0 += 4) {
        int jj = j0 + sub;
        int idx; float sgn, wgt;
        if (jj < CTX) { idx = o_words[jj * BATCH + b]; sgn = 1.0f; wgt = 1.0f / CTX; }
        else { idx = n_words[b * (CTX * NEGS) + (jj - CTX)]; sgn = -1.0f; wgt = 1.0f / NEGS; }
        const char* obase = (const char*)W_os + (((unsigned)idx << 9) + ((unsigned)t << 5));
        float4 o0 = *(const float4*)(obase);
        float4 o1 = *(const float4*)(obase + 16);
        float p = i0.x*o0.x + i0.y*o0.y + i0.z*o0.z + i0.w*o0.w
                + i1.x*o1.x + i1.y*o1.y + i1.z*o1.z + i1.w*o1.w;
        p += __shfl_xor(p, 1); p += __shfl_xor(p, 2);
        p += __shfl_xor(p, 4); p += __shfl_xor(p, 8);
        acc += (t == 0) ? wgt * log_sigmoid_fast(sgn * p) : 0.0f;
    }
    acc += __shfl_xor(acc, 16);
    acc += __shfl_xor(acc, 32);
    __shared__ float ws[4];
    if (lane == 0) ws[wave] = acc;
    __syncthreads();
    if (threadIdx.x == 0) atomicAdd(out, -(ws[0] + ws[1] + ws[2] + ws[3]));
}

extern "C" void kernel_launch(void* const* d_in, const int* in_sizes, int n_in,
                              void* d_out, int out_size, void* d_ws, size_t ws_size,
                              hipStream_t stream) {
    const int*   i_words = (const int*)d_in[0];
    const int*   o_words = (const int*)d_in[1];
    const int*   n_words = (const int*)d_in[2];
    const float* W_i     = (const float*)d_in[3];
    const float* W_os    = (const float*)d_in[4];
    float* out = (float*)d_out;

    hipMemsetAsync(out, 0, sizeof(float), stream);

    if (ws_size < (size_t)WS_NEEDED) {
        sgns_loss_direct<<<2048, 256, 0, stream>>>(i_words, o_words, n_words, W_i, W_os, out);
        return;
    }

    char* ws = (char*)d_ws;
    unsigned* records  = (unsigned*)(ws + OFF_RECORDS);
    unsigned* counts   = (unsigned*)(ws + OFF_COUNTS);
    unsigned* spillcnt = (unsigned*)(ws + OFF_SPILLCNT);
    unsigned* spill    = (unsigned*)(ws + OFF_SPILL);
    float*    ivec     = (float*)(ws + OFF_IVEC);

    hipMemsetAsync(spillcnt, 0, sizeof(unsigned), stream);

    gather_ivec_kernel<<<512, 256, 0, stream>>>(i_words, (const float4*)W_i, (float4*)ivec);
    bucketize_kernel<<<P1B, 256, 0, stream>>>(o_words, n_words, records, counts, spillcnt, spill);
    bucket_loss_kernel<<<1024 + 8, 256, 0, stream>>>(W_os, ivec, records, counts, spillcnt, spill, out);
}

// Round 9
// 80.737 us; speedup vs baseline: 2.2300x; 1.0967x over previous
//
#include <hip/hip_runtime.h>
#include <math.h>

#define VOCAB 100000
#define DIM 128
#define BATCH 4096
#define CTX 20
#define NEGS 10
#define NTARG (CTX + CTX * NEGS)                 // 220
#define NPAIR_POS (CTX * BATCH)                  // 81920
#define NPAIR (NPAIR_POS + BATCH * CTX * NEGS)   // 901120
#define NB 32            // buckets: 3125 rows = 1.6 MB W_os slice each
#define ROWS_PER_B 3125
#define P1B 128          // pass-1 blocks (= cells per bucket)
#define PAIRS_PER_P1B (NPAIR / P1B)              // 7040
#define CAPB 384         // slots per cell; lambda=220 -> +11 sigma
#define SPILL_MAX 2048

// d_ws layout (bytes)
#define OFF_RECORDS  0u                          // u32[NB*P1B*CAPB] = 6291456
#define OFF_COUNTS   6291456u                    // u32[NB*P1B]      = 16384
#define OFF_SPILLCNT 6307840u                    // u32 (+pad)
#define OFF_SPILL    6308096u                    // u32[SPILL_MAX]   = 8192
#define OFF_IVEC     6316288u                    // f32[BATCH*DIM]   = 2097152
#define WS_NEEDED    8413440u

__device__ __forceinline__ float log_sigmoid_fast(float x) {
    float a = fabsf(x);
    return fminf(x, 0.0f) - __logf(1.0f + __expf(-a));
}

// ---- Kernel P: fused prep. blocks [0,512): ivec gather; [512,640): bucketize ----
__global__ __launch_bounds__(256) void prep_kernel(
    const int* __restrict__ i_words, const int* __restrict__ o_words,
    const int* __restrict__ n_words, const float4* __restrict__ W_i4,
    float4* __restrict__ ivec4, unsigned* __restrict__ records,
    unsigned* __restrict__ counts, unsigned* __restrict__ spillcnt,
    unsigned* __restrict__ spill)
{
    if (blockIdx.x < 512) {
        int tid = blockIdx.x * 256 + threadIdx.x;   // 131072 = BATCH*32
        int b = tid >> 5, q = tid & 31;
        int ic = i_words[b];
        ivec4[tid] = W_i4[ic * 32 + q];
        return;
    }
    const int bid = blockIdx.x - 512;               // 0..127

    __shared__ unsigned lcnt[NB];
    if (threadIdx.x < NB) lcnt[threadIdx.x] = 0;
    __syncthreads();

    const int base = bid * PAIRS_PER_P1B;
    const int end  = base + PAIRS_PER_P1B;
    for (int j = base + threadIdx.x; j < end; j += 256) {
        int row; unsigned rec;
        if (j < NPAIR_POS) {                        // o_words flat [C,B]: b = j & 4095
            row = o_words[j];
            rec = ((unsigned)row << 13) | ((unsigned)(j & (BATCH - 1)) << 1);
        } else {                                    // n_words flat [B, C*NEG]
            int jn = j - NPAIR_POS;
            row = n_words[jn];
            rec = ((unsigned)row << 13) | ((unsigned)(jn / (CTX * NEGS)) << 1) | 1u;
        }
        int bin = (unsigned)row / ROWS_PER_B;       // 0..31 (magic-mul div)
        unsigned slot = atomicAdd(&lcnt[bin], 1u);  // LDS atomic
        if (slot < CAPB) {
            records[((unsigned)bin * P1B + (unsigned)bid) * CAPB + slot] = rec;
        } else {
            unsigned s = atomicAdd(spillcnt, 1u);   // ~never taken
            if (s < SPILL_MAX) spill[s] = rec;
        }
    }
    __syncthreads();
    if (threadIdx.x < NB) {
        unsigned c = lcnt[threadIdx.x];
        counts[threadIdx.x * P1B + bid] = (c > CAPB) ? CAPB : c;
    }
}

// ---- Kernel C: XCD-affine, software-pipelined pair processing ----
// 2048 blocks: xcd = lid&7; s = lid>>3 (0..255); m = s>>1 cell-in-bucket; half = s&1.
// Walk 4 buckets per XCD in phase; 2 blocks per cell (stride-32 interleave).
__global__ __launch_bounds__(256) void bucket_loss_kernel(
    const float* __restrict__ W_os, const float* __restrict__ ivec,
    const unsigned* __restrict__ records, const unsigned* __restrict__ counts,
    const unsigned* __restrict__ spillcnt, const unsigned* __restrict__ spill,
    float* __restrict__ out)
{
    const int t    = threadIdx.x & 15;
    const int grp  = threadIdx.x >> 4;
    const int lane = threadIdx.x & 63;
    const int wave = threadIdx.x >> 6;
    const unsigned tb = (unsigned)t << 5;           // byte offset within row

    float acc = 0.0f;
    const int lid = blockIdx.x;

    if (lid < 2048) {
        const int xcd  = lid & 7;
        const int s    = lid >> 3;                  // 0..255
        const int m    = s >> 1;                    // cell within bucket 0..127
        const int half = s & 1;

        for (int bk = 0; bk < NB / 8; ++bk) {
            const int bucket = xcd * (NB / 8) + bk;
            const unsigned cell = (unsigned)bucket * P1B + m;
            const unsigned cnt = counts[cell];
            const unsigned* rbase = records + cell * CAPB;

            unsigned i = (unsigned)(grp + (half << 4));   // start 0..31, stride 32
            bool hA = i < cnt;
            bool hB = i + 32 < cnt;
            unsigned recA = hA ? rbase[i] : 0u;
            unsigned recB = hB ? rbase[i + 32] : 0u;
            float4 r0A, r1A, v0A, v1A;
            if (hA) {
                const char* rp = (const char*)W_os + (((recA >> 13) << 9) + tb);
                r0A = *(const float4*)rp; r1A = *(const float4*)(rp + 16);
                const char* vp = (const char*)ivec + ((((recA >> 1) & 4095u) << 9) + tb);
                v0A = *(const float4*)vp; v1A = *(const float4*)(vp + 16);
            }
            while (hA) {
                // rec prefetch 2 ahead
                bool hC = i + 64 < cnt;
                unsigned recC = hC ? rbase[i + 64] : 0u;
                // vector loads 1 ahead
                float4 r0B, r1B, v0B, v1B;
                if (hB) {
                    const char* rp = (const char*)W_os + (((recB >> 13) << 9) + tb);
                    r0B = *(const float4*)rp; r1B = *(const float4*)(rp + 16);
                    const char* vp = (const char*)ivec + ((((recB >> 1) & 4095u) << 9) + tb);
                    v0B = *(const float4*)vp; v1B = *(const float4*)(vp + 16);
                }
                // compute pair A
                float pd = r0A.x*v0A.x + r0A.y*v0A.y + r0A.z*v0A.z + r0A.w*v0A.w
                         + r1A.x*v1A.x + r1A.y*v1A.y + r1A.z*v1A.z + r1A.w*v1A.w;
                pd += __shfl_xor(pd, 1);
                pd += __shfl_xor(pd, 2);
                pd += __shfl_xor(pd, 4);
                pd += __shfl_xor(pd, 8);
                float term = (recA & 1u) ? (1.0f / NEGS) * log_sigmoid_fast(-pd)
                                         : (1.0f / CTX)  * log_sigmoid_fast(pd);
                if (t == 0) acc += term;
                // rotate
                recA = recB; recB = recC; hA = hB; hB = hC;
                r0A = r0B; r1A = r1B; v0A = v0B; v1A = v1B;
                i += 32;
            }
        }
    } else {
        // spill blocks (exactness guarantee; expected empty)
        int sg = (lid - 2048) * 16 + grp;           // 0..127
        unsigned ns = *spillcnt; if (ns > SPILL_MAX) ns = SPILL_MAX;
        for (unsigned s = sg; s < ns; s += 128) {
            unsigned rec = spill[s];
            const char* rp = (const char*)W_os + (((rec >> 13) << 9) + tb);
            float4 r0 = *(const float4*)rp, r1 = *(const float4*)(rp + 16);
            const char* vp = (const char*)ivec + ((((rec >> 1) & 4095u) << 9) + tb);
            float4 v0 = *(const float4*)vp, v1 = *(const float4*)(vp + 16);
            float pd = r0.x*v0.x + r0.y*v0.y + r0.z*v0.z + r0.w*v0.w
                     + r1.x*v1.x + r1.y*v1.y + r1.z*v1.z + r1.w*v1.w;
            pd += __shfl_xor(pd, 1);
            pd += __shfl_xor(pd, 2);
            pd += __shfl_xor(pd, 4);
            pd += __shfl_xor(pd, 8);
            float term = (rec & 1u) ? (1.0f / NEGS) * log_sigmoid_fast(-pd)
                                    : (1.0f / CTX)  * log_sigmoid_fast(pd);
            if (t == 0) acc += term;
        }
    }

    acc += __shfl_xor(acc, 16);
    acc += __shfl_xor(acc, 32);
    __shared__ float wsum[4];
    if (lane == 0) wsum[wave] = acc;
    __syncthreads();
    if (threadIdx.x == 0) {
        float sum = wsum[0] + wsum[1] + wsum[2] + wsum[3];
        if (sum != 0.0f) atomicAdd(out, -sum);
    }
}

// ---- Fallback (round-5 direct kernel) if ws too small ----
__global__ __launch_bounds__(256) void sgns_loss_direct(
    const int* __restrict__ i_words, const int* __restrict__ o_words,
    const int* __restrict__ n_words, const float* __restrict__ W_i,
    const float* __restrict__ W_os, float* __restrict__ out)
{
    const int lane = threadIdx.x & 63;
    const int wave = threadIdx.x >> 6;
    const int w    = blockIdx.x * 4 + wave;
    const int b    = w >> 1;
    const int h    = w & 1;
    const int sub = lane >> 4;
    const int t   = lane & 15;
    const int j_begin = h ? 112 : 0;
    const int j_end   = h ? NTARG : 112;
    float acc = 0.0f;
    const int ic = i_words[b];
    const char* ibase = (const char*)W_i + (((unsigned)ic << 9) + ((unsigned)t << 5));
    float4 i0 = *(const float4*)(ibase);
    float4 i1 = *(const float4*)(ibase + 16);
    #pragma unroll 4
    for (int j0 = j_begin; j0 < j_end; j0 += 4) {
        int jj = j0 + sub;
        int idx; float sgn, wgt;
        if (jj < CTX) { idx = o_words[jj * BATCH + b]; sgn = 1.0f; wgt = 1.0f / CTX; }
        else { idx = n_words[b * (CTX * NEGS) + (jj - CTX)]; sgn = -1.0f; wgt = 1.0f / NEGS; }
        const char* obase = (const char*)W_os + (((unsigned)idx << 9) + ((unsigned)t << 5));
        float4 o0 = *(const float4*)(obase);
        float4 o1 = *(const float4*)(obase + 16);
        float p = i0.x*o0.x + i0.y*o0.y + i0.z*o0.z + i0.w*o0.w
                + i1.x*o1.x + i1.y*o1.y + i1.z*o1.z + i1.w*o1.w;
        p += __shfl_xor(p, 1); p += __shfl_xor(p, 2);
        p += __shfl_xor(p, 4); p += __shfl_xor(p, 8);
        acc += (t == 0) ? wgt * log_sigmoid_fast(sgn * p) : 0.0f;
    }
    acc += __shfl_xor(acc, 16);
    acc += __shfl_xor(acc, 32);
    __shared__ float ws[4];
    if (lane == 0) ws[wave] = acc;
    __syncthreads();
    if (threadIdx.x == 0) atomicAdd(out, -(ws[0] + ws[1] + ws[2] + ws[3]));
}

extern "C" void kernel_launch(void* const* d_in, const int* in_sizes, int n_in,
                              void* d_out, int out_size, void* d_ws, size_t ws_size,
                              hipStream_t stream) {
    const int*   i_words = (const int*)d_in[0];
    const int*   o_words = (const int*)d_in[1];
    const int*   n_words = (const int*)d_in[2];
    const float* W_i     = (const float*)d_in[3];
    const float* W_os    = (const float*)d_in[4];
    float* out = (float*)d_out;

    hipMemsetAsync(out, 0, sizeof(float), stream);

    if (ws_size < (size_t)WS_NEEDED) {
        sgns_loss_direct<<<2048, 256, 0, stream>>>(i_words, o_words, n_words, W_i, W_os, out);
        return;
    }

    char* ws = (char*)d_ws;
    unsigned* records  = (unsigned*)(ws + OFF_RECORDS);
    unsigned* counts   = (unsigned*)(ws + OFF_COUNTS);
    unsigned* spillcnt = (unsigned*)(ws + OFF_SPILLCNT);
    unsigned* spill    = (unsigned*)(ws + OFF_SPILL);
    float*    ivec     = (float*)(ws + OFF_IVEC);

    hipMemsetAsync(spillcnt, 0, sizeof(unsigned), stream);

    prep_kernel<<<640, 256, 0, stream>>>(i_words, o_words, n_words,
                                         (const float4*)W_i, (float4*)ivec,
                                         records, counts, spillcnt, spill);
    bucket_loss_kernel<<<2048 + 8, 256, 0, stream>>>(W_os, ivec, records, counts,
                                                     spillcnt, spill, out);
}